// Round 10
// baseline (139.961 us; speedup 1.0000x reference)
//
#include <hip/hip_runtime.h>
#include <cmath>

// ---- types -----------------------------------------------------------------
typedef float  f32x4  __attribute__((ext_vector_type(4)));
typedef __bf16 bf16x8 __attribute__((ext_vector_type(8)));
typedef __bf16 bf16x4 __attribute__((ext_vector_type(4)));
typedef __bf16 bf16x2 __attribute__((ext_vector_type(2)));

#define MFMA16(acc, a, b) (acc) = __builtin_amdgcn_mfma_f32_16x16x32_bf16((a), (b), (acc), 0, 0, 0)

// Geometry: x [B=2, C=128, D=16, H=64, W=64] fp32; flat = b*8388608 + c*65536 + d*4096 + hw.
// qkv_w rows: head h occupies [96h, 96h+96): q +0, k +32, v +64.
// Attention-output channel numbering: ch = 32h + d (head-major).

// LDS swizzles (XOR keeps 16B-aligned access conflict-light, T2/G4)
__device__ __forceinline__ int swz(int row, int colByte){ return row*256 + (colByte ^ ((row & 7) << 4)); }   // pitch 256B
__device__ __forceinline__ int swzP(int row, int colByte){ return row*128 + (colByte ^ ((row & 7) << 4)); }  // pitch 128B

// coalesced fp32 x-tile load: 64 pos x 128 ch; thread t: pos=t&63 (256B/instr), 32 floats
__device__ __forceinline__ void loadx(float* sx, const float* __restrict__ xb, int t){
  int p = t & 63, cg = t >> 6;
  const float* col = xb + p;
  #pragma unroll
  for (int i = 0; i < 4; ++i)
    #pragma unroll
    for (int j = 0; j < 8; ++j)
      sx[i*8 + j] = col[(cg*8 + i*32 + j) * 65536];
}
// cvt + LDS write of staged regs -> bf16 [pos][ch] swizzled tile
__device__ __forceinline__ void writex(const float* sx, char* ldsX, int t){
  int p = t & 63, cg = t >> 6;
  #pragma unroll
  for (int i = 0; i < 4; ++i){
    bf16x8 u;
    #pragma unroll
    for (int j = 0; j < 8; ++j) u[j] = (__bf16)sx[i*8 + j];
    *(bf16x8*)(ldsX + swz(p, cg*16 + i*64)) = u;
  }
}

// ---- W-prep: fp32 weights -> bf16 once (qkv_w | o1w | o2w concatenated) ----
__global__ __launch_bounds__(256) void wprep(const float* __restrict__ qkv_w,
                                             const float* __restrict__ o1w,
                                             const float* __restrict__ o2w,
                                             __bf16* __restrict__ w16){
  int e = (blockIdx.x * 256 + threadIdx.x) * 4;   // 80 blocks -> 81920 elems
  const float* src; int off;
  if (e < 49152)      { src = qkv_w; off = e; }
  else if (e < 65536) { src = o1w;   off = e - 49152; }
  else                { src = o2w;   off = e - 65536; }
  f32x4 v = *(const f32x4*)(src + off);
  bf16x4 o;
  #pragma unroll
  for (int r = 0; r < 4; ++r) o[r] = (__bf16)v[r];
  *(bf16x4*)(w16 + e) = o;
}

// ---- K1: k/v projection + LayerNorm + per-block kv partial -----------------
// grid 2048 = 32 bd x 64 tiles of 64 pos, single chunk, 2 barriers (r9, ~33us).
// LDS 32K: x tile 16K (per-wave v' overlaid after S_b), 4x4K k' scratch.
// Partials go to d_out (16MB scratch, k2 overwrites it later in the launch).
__global__ __launch_bounds__(256) void k1_kv(
    const float* __restrict__ x, const __bf16* __restrict__ w16, const float* __restrict__ qkv_b,
    const float* __restrict__ klw, const float* __restrict__ klb,
    const float* __restrict__ vlw, const float* __restrict__ vlb,
    __bf16* __restrict__ part){
  __shared__ char ldsX[16384];     // x [64 pos][256B] -> per-wave v' [32][64] @ w*4096
  __shared__ char ksS[4][4096];    // per-wave k' [32 ch][64 pos] bf16, pitch 128B
  int t = threadIdx.x, lane = t & 63, w = t >> 6, l15 = lane & 15, l4 = lane >> 4;
  int bx = blockIdx.x, bd = bx >> 6, b = bd >> 4, d = bd & 15;
  const float* xb = x + (size_t)b*8388608 + d*4096 + (bx & 63)*64;
  char* ks = ksS[w];
  char* vs = ldsX + w * 4096;

  {
    float sx[32];
    loadx(sx, xb, t);
    writex(sx, ldsX, t);
  }
  __syncthreads();                                  // S_a: x staged

  bf16x4 pv0[4], pv1[4];           // v' packed bf16, lives across S_b (8 VGPRs)
  // ---- phase 0: k -> LN -> ks (write now); phase 1: v -> LN -> pack -------
  #pragma unroll
  for (int ph = 0; ph < 2; ++ph){
    int po = 96*w + 32 + 32*ph;
    f32x4 acc[2][4] = {};
    #pragma unroll
    for (int kf = 0; kf < 4; ++kf){
      bf16x8 a0 = *(const bf16x8*)(w16 + (po + l15)*128 + kf*32 + l4*8);
      bf16x8 a1 = *(const bf16x8*)(w16 + (po + 16 + l15)*128 + kf*32 + l4*8);
      bf16x8 bn0 = *(const bf16x8*)(ldsX + swz(l15,      kf*64 + l4*16));
      bf16x8 bn1 = *(const bf16x8*)(ldsX + swz(16 + l15, kf*64 + l4*16));
      bf16x8 bn2 = *(const bf16x8*)(ldsX + swz(32 + l15, kf*64 + l4*16));
      bf16x8 bn3 = *(const bf16x8*)(ldsX + swz(48 + l15, kf*64 + l4*16));
      MFMA16(acc[0][0], a0, bn0); MFMA16(acc[0][1], a0, bn1);
      MFMA16(acc[0][2], a0, bn2); MFMA16(acc[0][3], a0, bn3);
      MFMA16(acc[1][0], a1, bn0); MFMA16(acc[1][1], a1, bn1);
      MFMA16(acc[1][2], a1, bn2); MFMA16(acc[1][3], a1, bn3);
    }
    const float* lwp = (ph ? vlw : klw) + 32*w;
    const float* lbp = (ph ? vlb : klb) + 32*w;
    f32x4 b0  = *(const f32x4*)(qkv_b + po + l4*4);
    f32x4 b1  = *(const f32x4*)(qkv_b + po + 16 + l4*4);
    f32x4 lw0 = *(const f32x4*)(lwp + l4*4), lw1 = *(const f32x4*)(lwp + 16 + l4*4);
    f32x4 lb0 = *(const f32x4*)(lbp + l4*4), lb1 = *(const f32x4*)(lbp + 16 + l4*4);
    #pragma unroll
    for (int n = 0; n < 4; ++n){
      f32x4 v0 = acc[0][n] + b0;
      f32x4 v1 = acc[1][n] + b1;
      // LN over 32 ch per pos (ddof=1, denom = std+eps): in-lane 8 + xor 16,32
      float s1 = v0[0]+v0[1]+v0[2]+v0[3] + v1[0]+v1[1]+v1[2]+v1[3];
      float s2 = v0[0]*v0[0]+v0[1]*v0[1]+v0[2]*v0[2]+v0[3]*v0[3]
               + v1[0]*v1[0]+v1[1]*v1[1]+v1[2]*v1[2]+v1[3]*v1[3];
      s1 += __shfl_xor(s1, 16); s2 += __shfl_xor(s2, 16);
      s1 += __shfl_xor(s1, 32); s2 += __shfl_xor(s2, 32);
      float m   = s1 * (1.f/32.f);
      float var = fmaxf((s2 - 32.f*m*m) * (1.f/31.f), 0.f);
      float inv = 1.f / (sqrtf(var) + 1e-5f);
      v0 = (v0 - m) * inv * lw0 + lb0;
      v1 = (v1 - m) * inv * lw1 + lb1;
      if (ph == 0){
        int pB = (16*n + l15) * 2;
        #pragma unroll
        for (int r = 0; r < 4; ++r){
          *(__bf16*)(ks + swzP(l4*4 + r, pB))      = (__bf16)v0[r];
          *(__bf16*)(ks + swzP(16 + l4*4 + r, pB)) = (__bf16)v1[r];
        }
      } else {
        #pragma unroll
        for (int r = 0; r < 4; ++r){ pv0[n][r] = (__bf16)v0[r]; pv1[n][r] = (__bf16)v1[r]; }
      }
    }
  }
  __syncthreads();                                  // S_b: all x reads done; overlay v'
  #pragma unroll
  for (int n = 0; n < 4; ++n){
    int pB = (16*n + l15) * 2;
    #pragma unroll
    for (int r = 0; r < 4; ++r){
      *(__bf16*)(vs + swzP(l4*4 + r, pB))      = pv0[n][r];
      *(__bf16*)(vs + swzP(16 + l4*4 + r, pB)) = pv1[n][r];
    }
  }
  // outer product kv[d][c] = sum_pos v'[d,pos] k'[c,pos] (K=64);
  // same-wave ds_write->ds_read (in-order DS pipe), no barrier needed.
  f32x4 kv[2][2] = {};
  #pragma unroll
  for (int kf = 0; kf < 2; ++kf){
    bf16x8 av0 = *(const bf16x8*)(vs + swzP(l15,      kf*64 + l4*16));
    bf16x8 av1 = *(const bf16x8*)(vs + swzP(16 + l15, kf*64 + l4*16));
    bf16x8 bk0 = *(const bf16x8*)(ks + swzP(l15,      kf*64 + l4*16));
    bf16x8 bk1 = *(const bf16x8*)(ks + swzP(16 + l15, kf*64 + l4*16));
    MFMA16(kv[0][0], av0, bk0); MFMA16(kv[0][1], av0, bk1);
    MFMA16(kv[1][0], av1, bk0); MFMA16(kv[1][1], av1, bk1);
  }

  // store partial: part[bx][h=w][d][c], c fast (matches kvt layout)
  __bf16* pb = part + (size_t)bx*4096 + w*1024;
  #pragma unroll
  for (int m = 0; m < 2; ++m)
    #pragma unroll
    for (int n = 0; n < 2; ++n)
      #pragma unroll
      for (int r = 0; r < 4; ++r)
        pb[(16*m + l4*4 + r)*32 + 16*n + l15] = (__bf16)kv[m][n][r];
}

// ---- K1.5: reduce 64 partials -> kvt f32 [bd][h][d][c], /4096 --------------
__global__ __launch_bounds__(256) void k15_reduce(const __bf16* __restrict__ part,
                                                  float* __restrict__ kvt){
  int bx = blockIdx.x, t = threadIdx.x;
  int bd = bx >> 3, seg = bx & 7;
  int e = seg * 512 + t * 2;
  float s0 = 0.f, s1 = 0.f;
  #pragma unroll
  for (int sub = 0; sub < 64; ++sub){
    bf16x2 p = *(const bf16x2*)(part + (size_t)(bd * 64 + sub) * 4096 + e);
    s0 += (float)p[0]; s1 += (float)p[1];
  }
  kvt[bd * 4096 + e]     = s0 * (1.f / 4096.f);
  kvt[bd * 4096 + e + 1] = s1 * (1.f / 4096.f);
}

// ---- K2: q -> attention(+x) -> o1+gelu -> o2 + bias + x --------------------
// grid 2048, one 64-pos tile per block; block 256 = 4 waves.
// RESTRUCTURED (r9: 52us at 4 barriers, lockstep latency-bound): after x is
// staged, each wave owns 16 positions and runs Q -> attn -> O1+gelu for ALL
// 128 channels in its own 4KB LDS slice (same-wave DS ordering, no barriers,
// waves drift and cross-hide latency). One barrier when h is complete, then
// O2 keeps the proven channel-split coalesced store. Barriers 4 -> 2.
__global__ __launch_bounds__(256) void k2_main(
    const float* __restrict__ x, const __bf16* __restrict__ w16, const float* __restrict__ qkv_b,
    const float* __restrict__ o1b, const float* __restrict__ o2b,
    const float* __restrict__ kvt, float* __restrict__ out){
  __shared__ char lx[16384];   // x tile [64 pos][128 ch] bf16 (residual source, persists)
  __shared__ char wk[16384];   // 4 x 4KB wave slices: [16 pos][128 ch] q -> ret -> h
  int t = threadIdx.x, lane = t & 63, w = t >> 6, l15 = lane & 15, l4 = lane >> 4;
  int bx = blockIdx.x, bd = bx >> 6, b = bd >> 4, d = bd & 15;
  size_t gofs = (size_t)b*8388608 + d*4096 + (bx & 63)*64;
  const float* xb = x + gofs;
  float* ob = out + gofs;
  const __bf16* w1 = w16 + 49152;
  const __bf16* w2 = w16 + 65536;
  char* s = wk + w * 4096;     // own slice (pos w*16 .. w*16+15)

  {
    float sx[32];
    loadx(sx, xb, t);
    writex(sx, lx, t);
  }
  __syncthreads();                                  // S0: x staged

  // ---- Q: all 128 q-channels (head-major ch = 32h+d) for own 16 pos -------
  {
    f32x4 acc[8] = {};
    #pragma unroll
    for (int kf = 0; kf < 4; ++kf){
      bf16x8 bq = *(const bf16x8*)(lx + swz(w*16 + l15, kf*64 + l4*16));
      #pragma unroll
      for (int m = 0; m < 8; ++m){
        bf16x8 a = *(const bf16x8*)(w16 + (96*(m>>1) + (m&1)*16 + l15)*128 + kf*32 + l4*8);
        MFMA16(acc[m], a, bq);
      }
    }
    #pragma unroll
    for (int m = 0; m < 8; ++m){
      f32x4 qb = *(const f32x4*)(qkv_b + 96*(m>>1) + (m&1)*16 + l4*4);
      int ch0 = 32*(m>>1) + (m&1)*16 + l4*4;
      bf16x4 pk;
      #pragma unroll
      for (int r = 0; r < 4; ++r) pk[r] = (__bf16)(acc[m][r] + qb[r]);
      *(bf16x4*)(s + swz(l15, ch0*2)) = pk;
    }
  }

  // ---- attn per head: ret[d][pos] = kv . q, += x residual ------------------
  {
    const float* kvb = kvt + (size_t)bd*4096;
    #pragma unroll
    for (int h = 0; h < 4; ++h){
      const float* kvh = kvb + h*1024;
      f32x4 ql0 = *(const f32x4*)(kvh + l15*32 + l4*8);
      f32x4 qh0 = *(const f32x4*)(kvh + l15*32 + l4*8 + 4);
      f32x4 ql1 = *(const f32x4*)(kvh + (16 + l15)*32 + l4*8);
      f32x4 qh1 = *(const f32x4*)(kvh + (16 + l15)*32 + l4*8 + 4);
      bf16x8 ka0, ka1;
      #pragma unroll
      for (int j = 0; j < 4; ++j){
        ka0[j] = (__bf16)ql0[j]; ka0[j+4] = (__bf16)qh0[j];
        ka1[j] = (__bf16)ql1[j]; ka1[j+4] = (__bf16)qh1[j];
      }
      bf16x8 bq = *(const bf16x8*)(s + swz(l15, h*64 + l4*16));
      f32x4 r0 = {}, r1 = {};
      MFMA16(r0, ka0, bq);
      MFMA16(r1, ka1, bq);
      int ch0 = 32*h + l4*4;
      bf16x4 xv0 = *(const bf16x4*)(lx + swz(w*16 + l15, ch0*2));
      bf16x4 xv1 = *(const bf16x4*)(lx + swz(w*16 + l15, (ch0 + 16)*2));
      bf16x4 p0, p1;
      #pragma unroll
      for (int r = 0; r < 4; ++r){
        p0[r] = (__bf16)(r0[r] + (float)xv0[r]);
        p1[r] = (__bf16)(r1[r] + (float)xv1[r]);
      }
      *(bf16x4*)(s + swz(l15, ch0*2)) = p0;
      *(bf16x4*)(s + swz(l15, (ch0 + 16)*2)) = p1;
    }
  }

  // ---- O1 + gelu: all 128 h-channels for own 16 pos ------------------------
  {
    bf16x8 bn[4];
    #pragma unroll
    for (int kf = 0; kf < 4; ++kf)
      bn[kf] = *(const bf16x8*)(s + swz(l15, kf*64 + l4*16));
    f32x4 acc[8] = {};
    #pragma unroll
    for (int kf = 0; kf < 4; ++kf)
      #pragma unroll
      for (int m = 0; m < 8; ++m){
        bf16x8 a = *(const bf16x8*)(w1 + (16*m + l15)*128 + kf*32 + l4*8);
        MFMA16(acc[m], a, bn[kf]);
      }
    #pragma unroll
    for (int m = 0; m < 8; ++m){
      f32x4 bb = *(const f32x4*)(o1b + 16*m + l4*4);
      bf16x4 pk;
      #pragma unroll
      for (int r = 0; r < 4; ++r){
        float v = acc[m][r] + bb[r];
        float z = v * (1.5957691216f + 0.0713548164f * v * v);   // tanh-GELU
        pk[r] = (__bf16)(v / (1.f + __expf(-z)));
      }
      *(bf16x4*)(s + swz(l15, (16*m + l4*4)*2)) = pk;
    }
  }
  __syncthreads();                                  // S_h: all slices' h complete

  // ---- O2 + bias + residual: own 32 channels x 64 pos, coalesced store ----
  {
    int oo = 32 * w;
    f32x4 acc2[2][4] = {};
    #pragma unroll
    for (int kf = 0; kf < 4; ++kf){
      bf16x8 a0 = *(const bf16x8*)(w2 + (oo + l15)*128 + kf*32 + l4*8);
      bf16x8 a1 = *(const bf16x8*)(w2 + (oo + 16 + l15)*128 + kf*32 + l4*8);
      bf16x8 bn0 = *(const bf16x8*)(wk +        swz(l15, kf*64 + l4*16));
      bf16x8 bn1 = *(const bf16x8*)(wk + 4096 + swz(l15, kf*64 + l4*16));
      bf16x8 bn2 = *(const bf16x8*)(wk + 8192 + swz(l15, kf*64 + l4*16));
      bf16x8 bn3 = *(const bf16x8*)(wk + 12288 + swz(l15, kf*64 + l4*16));
      MFMA16(acc2[0][0], a0, bn0); MFMA16(acc2[0][1], a0, bn1);
      MFMA16(acc2[0][2], a0, bn2); MFMA16(acc2[0][3], a0, bn3);
      MFMA16(acc2[1][0], a1, bn0); MFMA16(acc2[1][1], a1, bn1);
      MFMA16(acc2[1][2], a1, bn2); MFMA16(acc2[1][3], a1, bn3);
    }
    #pragma unroll
    for (int m = 0; m < 2; ++m){
      int c0 = oo + 16*m + l4*4;
      f32x4 bb = *(const f32x4*)(o2b + c0);
      #pragma unroll
      for (int n = 0; n < 4; ++n){
        bf16x4 xv = *(const bf16x4*)(lx + swz(16*n + l15, c0*2));
        #pragma unroll
        for (int r = 0; r < 4; ++r)
          ob[(size_t)(c0 + r)*65536 + 16*n + l15] = acc2[m][n][r] + bb[r] + (float)xv[r];
      }
    }
  }
}

// ---- launch ----------------------------------------------------------------
extern "C" void kernel_launch(void* const* d_in, const int* in_sizes, int n_in,
                              void* d_out, int out_size, void* d_ws, size_t ws_size,
                              hipStream_t stream){
  const float* x     = (const float*)d_in[0];
  const float* qkv_w = (const float*)d_in[1];
  const float* qkv_b = (const float*)d_in[2];
  const float* o1w   = (const float*)d_in[3];
  const float* o1b   = (const float*)d_in[4];
  const float* o2w   = (const float*)d_in[5];
  const float* o2b   = (const float*)d_in[6];
  const float* klw   = (const float*)d_in[7];
  const float* klb   = (const float*)d_in[8];
  const float* vlw   = (const float*)d_in[9];
  const float* vlb   = (const float*)d_in[10];

  // part (16 MiB) lives in d_out scratch space: written by k1, read by k15,
  // then k2 overwrites ALL of d_out later in the same stream-ordered launch.
  __bf16* part = (__bf16*)d_out;                       // 2048*4096*2 = 16 MiB < 64 MiB
  float*  kvt  = (float*)d_ws;                         // 32*4096*4 = 512 KiB
  __bf16* w16  = (__bf16*)((char*)d_ws + 524288);      // 81920*2   = 160 KiB

  wprep<<<80, 256, 0, stream>>>(qkv_w, o1w, o2w, w16);
  k1_kv<<<2048, 256, 0, stream>>>(x, w16, qkv_b, klw, klb, vlw, vlb, part);
  k15_reduce<<<256, 256, 0, stream>>>(part, kvt);
  k2_main<<<2048, 256, 0, stream>>>(x, w16, qkv_b, o1b, o2b, kvt, (float*)d_out);
}

// Round 11
// 99.275 us; speedup vs baseline: 1.4098x; 1.4098x over previous
//
#include <hip/hip_runtime.h>
#include <cmath>

// ---- types -----------------------------------------------------------------
typedef float  f32x4  __attribute__((ext_vector_type(4)));
typedef __bf16 bf16x8 __attribute__((ext_vector_type(8)));
typedef __bf16 bf16x4 __attribute__((ext_vector_type(4)));
typedef __bf16 bf16x2 __attribute__((ext_vector_type(2)));

#define MFMA16(acc, a, b) (acc) = __builtin_amdgcn_mfma_f32_16x16x32_bf16((a), (b), (acc), 0, 0, 0)

// Geometry: x [B=2, C=128, D=16, H=64, W=64] fp32; flat = b*8388608 + c*65536 + d*4096 + hw.
// qkv_w rows: head h occupies [96h, 96h+96): q +0, k +32, v +64.
// Attention-output channel numbering: ch = 32h + d (head-major).

// LDS swizzles (XOR keeps 16B-aligned access conflict-light, T2/G4)
__device__ __forceinline__ int swz(int row, int colByte){ return row*256 + (colByte ^ ((row & 7) << 4)); }   // pitch 256B
__device__ __forceinline__ int swzP(int row, int colByte){ return row*128 + (colByte ^ ((row & 7) << 4)); }  // pitch 128B

// coalesced fp32 x-tile load: 64 pos x 128 ch; thread t: pos=t&63 (256B/instr), 32 floats
__device__ __forceinline__ void loadx(float* sx, const float* __restrict__ xb, int t){
  int p = t & 63, cg = t >> 6;
  const float* col = xb + p;
  #pragma unroll
  for (int i = 0; i < 4; ++i)
    #pragma unroll
    for (int j = 0; j < 8; ++j)
      sx[i*8 + j] = col[(cg*8 + i*32 + j) * 65536];
}
// cvt + LDS write of staged regs -> bf16 [pos][ch] swizzled tile
__device__ __forceinline__ void writex(const float* sx, char* ldsX, int t){
  int p = t & 63, cg = t >> 6;
  #pragma unroll
  for (int i = 0; i < 4; ++i){
    bf16x8 u;
    #pragma unroll
    for (int j = 0; j < 8; ++j) u[j] = (__bf16)sx[i*8 + j];
    *(bf16x8*)(ldsX + swz(p, cg*16 + i*64)) = u;
  }
}

// ---- W-prep: fp32 weights -> bf16 once (qkv_w | o1w | o2w concatenated) ----
__global__ __launch_bounds__(256) void wprep(const float* __restrict__ qkv_w,
                                             const float* __restrict__ o1w,
                                             const float* __restrict__ o2w,
                                             __bf16* __restrict__ w16){
  int e = (blockIdx.x * 256 + threadIdx.x) * 4;   // 80 blocks -> 81920 elems
  const float* src; int off;
  if (e < 49152)      { src = qkv_w; off = e; }
  else if (e < 65536) { src = o1w;   off = e - 49152; }
  else                { src = o2w;   off = e - 65536; }
  f32x4 v = *(const f32x4*)(src + off);
  bf16x4 o;
  #pragma unroll
  for (int r = 0; r < 4; ++r) o[r] = (__bf16)v[r];
  *(bf16x4*)(w16 + e) = o;
}

// ---- K1: k/v projection + LayerNorm + per-block kv partial -----------------
// grid 2048 = 32 bd x 64 tiles of 64 pos, single chunk, 2 barriers (r9 ~33us).
// nh-SPLIT: projection accumulators cover 32 pos at a time (acc[2][2], 16
// VGPR live) instead of 64 (32 VGPR) -> target VGPR <=128 (4 waves/SIMD,
// was 152 -> 3). A-frags reload per half (L2-hot, cheap).
// LDS 32K: x tile 16K (per-wave v' overlaid after S_b), 4x4K k' scratch.
__global__ __launch_bounds__(256) void k1_kv(
    const float* __restrict__ x, const __bf16* __restrict__ w16, const float* __restrict__ qkv_b,
    const float* __restrict__ klw, const float* __restrict__ klb,
    const float* __restrict__ vlw, const float* __restrict__ vlb,
    __bf16* __restrict__ part){
  __shared__ char ldsX[16384];     // x [64 pos][256B] -> per-wave v' [32][64] @ w*4096
  __shared__ char ksS[4][4096];    // per-wave k' [32 ch][64 pos] bf16, pitch 128B
  int t = threadIdx.x, lane = t & 63, w = t >> 6, l15 = lane & 15, l4 = lane >> 4;
  int bx = blockIdx.x, bd = bx >> 6, b = bd >> 4, d = bd & 15;
  const float* xb = x + (size_t)b*8388608 + d*4096 + (bx & 63)*64;
  char* ks = ksS[w];
  char* vs = ldsX + w * 4096;

  {
    float sx[32];
    loadx(sx, xb, t);
    writex(sx, ldsX, t);
  }
  __syncthreads();                                  // S_a: x staged

  bf16x4 pv0[4], pv1[4];           // v' packed bf16, lives across S_b (8 VGPRs)
  // ---- phase 0: k -> LN -> ks (write now); phase 1: v -> LN -> pack -------
  #pragma unroll
  for (int ph = 0; ph < 2; ++ph){
    int po = 96*w + 32 + 32*ph;
    #pragma unroll
    for (int nh = 0; nh < 2; ++nh){
      f32x4 acc[2][2] = {};
      #pragma unroll
      for (int kf = 0; kf < 4; ++kf){
        bf16x8 a0 = *(const bf16x8*)(w16 + (po + l15)*128 + kf*32 + l4*8);
        bf16x8 a1 = *(const bf16x8*)(w16 + (po + 16 + l15)*128 + kf*32 + l4*8);
        bf16x8 bn0 = *(const bf16x8*)(ldsX + swz(32*nh + l15,      kf*64 + l4*16));
        bf16x8 bn1 = *(const bf16x8*)(ldsX + swz(32*nh + 16 + l15, kf*64 + l4*16));
        MFMA16(acc[0][0], a0, bn0); MFMA16(acc[0][1], a0, bn1);
        MFMA16(acc[1][0], a1, bn0); MFMA16(acc[1][1], a1, bn1);
      }
      const float* lwp = (ph ? vlw : klw) + 32*w;
      const float* lbp = (ph ? vlb : klb) + 32*w;
      f32x4 b0  = *(const f32x4*)(qkv_b + po + l4*4);
      f32x4 b1  = *(const f32x4*)(qkv_b + po + 16 + l4*4);
      f32x4 lw0 = *(const f32x4*)(lwp + l4*4), lw1 = *(const f32x4*)(lwp + 16 + l4*4);
      f32x4 lb0 = *(const f32x4*)(lbp + l4*4), lb1 = *(const f32x4*)(lbp + 16 + l4*4);
      #pragma unroll
      for (int nn = 0; nn < 2; ++nn){
        int n = 2*nh + nn;
        f32x4 v0 = acc[0][nn] + b0;
        f32x4 v1 = acc[1][nn] + b1;
        // LN over 32 ch per pos (ddof=1, denom = std+eps): in-lane 8 + xor 16,32
        float s1 = v0[0]+v0[1]+v0[2]+v0[3] + v1[0]+v1[1]+v1[2]+v1[3];
        float s2 = v0[0]*v0[0]+v0[1]*v0[1]+v0[2]*v0[2]+v0[3]*v0[3]
                 + v1[0]*v1[0]+v1[1]*v1[1]+v1[2]*v1[2]+v1[3]*v1[3];
        s1 += __shfl_xor(s1, 16); s2 += __shfl_xor(s2, 16);
        s1 += __shfl_xor(s1, 32); s2 += __shfl_xor(s2, 32);
        float m   = s1 * (1.f/32.f);
        float var = fmaxf((s2 - 32.f*m*m) * (1.f/31.f), 0.f);
        float inv = 1.f / (sqrtf(var) + 1e-5f);
        v0 = (v0 - m) * inv * lw0 + lb0;
        v1 = (v1 - m) * inv * lw1 + lb1;
        if (ph == 0){
          int pB = (16*n + l15) * 2;
          #pragma unroll
          for (int r = 0; r < 4; ++r){
            *(__bf16*)(ks + swzP(l4*4 + r, pB))      = (__bf16)v0[r];
            *(__bf16*)(ks + swzP(16 + l4*4 + r, pB)) = (__bf16)v1[r];
          }
        } else {
          #pragma unroll
          for (int r = 0; r < 4; ++r){ pv0[n][r] = (__bf16)v0[r]; pv1[n][r] = (__bf16)v1[r]; }
        }
      }
    }
  }
  __syncthreads();                                  // S_b: all x reads done; overlay v'
  #pragma unroll
  for (int n = 0; n < 4; ++n){
    int pB = (16*n + l15) * 2;
    #pragma unroll
    for (int r = 0; r < 4; ++r){
      *(__bf16*)(vs + swzP(l4*4 + r, pB))      = pv0[n][r];
      *(__bf16*)(vs + swzP(16 + l4*4 + r, pB)) = pv1[n][r];
    }
  }
  // outer product kv[d][c] = sum_pos v'[d,pos] k'[c,pos] (K=64);
  // same-wave ds_write->ds_read (in-order DS pipe), no barrier needed.
  f32x4 kv[2][2] = {};
  #pragma unroll
  for (int kf = 0; kf < 2; ++kf){
    bf16x8 av0 = *(const bf16x8*)(vs + swzP(l15,      kf*64 + l4*16));
    bf16x8 av1 = *(const bf16x8*)(vs + swzP(16 + l15, kf*64 + l4*16));
    bf16x8 bk0 = *(const bf16x8*)(ks + swzP(l15,      kf*64 + l4*16));
    bf16x8 bk1 = *(const bf16x8*)(ks + swzP(16 + l15, kf*64 + l4*16));
    MFMA16(kv[0][0], av0, bk0); MFMA16(kv[0][1], av0, bk1);
    MFMA16(kv[1][0], av1, bk0); MFMA16(kv[1][1], av1, bk1);
  }

  // store partial: part[bx][h=w][d][c], c fast (matches kvt layout)
  __bf16* pb = part + (size_t)bx*4096 + w*1024;
  #pragma unroll
  for (int m = 0; m < 2; ++m)
    #pragma unroll
    for (int n = 0; n < 2; ++n)
      #pragma unroll
      for (int r = 0; r < 4; ++r)
        pb[(16*m + l4*4 + r)*32 + 16*n + l15] = (__bf16)kv[m][n][r];
}

// ---- K1.5: reduce 64 partials -> kvt f32 [bd][h][d][c], /4096 --------------
__global__ __launch_bounds__(256) void k15_reduce(const __bf16* __restrict__ part,
                                                  float* __restrict__ kvt){
  int bx = blockIdx.x, t = threadIdx.x;
  int bd = bx >> 3, seg = bx & 7;
  int e = seg * 512 + t * 2;
  float s0 = 0.f, s1 = 0.f;
  #pragma unroll
  for (int sub = 0; sub < 64; ++sub){
    bf16x2 p = *(const bf16x2*)(part + (size_t)(bd * 64 + sub) * 4096 + e);
    s0 += (float)p[0]; s1 += (float)p[1];
  }
  kvt[bd * 4096 + e]     = s0 * (1.f / 4096.f);
  kvt[bd * 4096 + e + 1] = s1 * (1.f / 4096.f);
}

// ---- K2: q -> attention(+x) -> o1+gelu -> o2 + bias + x --------------------
// grid 2048, one 64-pos tile per block; block 256 = 4 waves, wave w owns 32
// output channels per GEMM (r9 lockstep structure - r10's wave-independent
// variant QUADRUPLED weight loads with dependent chains: 52->100us. reverted).
// NEW: SINGLE 16KB LDS buffer. x residual for the wave's own 32-ch stripe is
// captured into 16 VGPRs (xr) before q/ret/h overlay the x tile. LDS 32->16KB:
// residency cap 5 -> 8 blocks/CU (if VGPR <= 64). 5 barriers.
__global__ __launch_bounds__(256) void k2_main(
    const float* __restrict__ x, const __bf16* __restrict__ w16, const float* __restrict__ qkv_b,
    const float* __restrict__ o1b, const float* __restrict__ o2b,
    const float* __restrict__ kvt, float* __restrict__ out){
  __shared__ char L[16384];    // x tile -> q/ret/h work buffer [64 pos][128 ch] bf16
  int t = threadIdx.x, lane = t & 63, w = t >> 6, l15 = lane & 15, l4 = lane >> 4;
  int bx = blockIdx.x, bd = bx >> 6, b = bd >> 4, d = bd & 15;
  size_t gofs = (size_t)b*8388608 + d*4096 + (bx & 63)*64;
  const float* xb = x + gofs;
  float* ob = out + gofs;
  const __bf16* w1 = w16 + 49152;
  const __bf16* w2 = w16 + 65536;
  int oo = 32 * w;

  {
    float sx[32];
    loadx(sx, xb, t);
    writex(sx, L, t);
  }
  // kv fragments: issued early, cvt f32->bf16 in-reg (A-frag: row d=l15, k=c)
  const float* kvh = kvt + ((size_t)bd*4 + w)*1024;
  f32x4 ql0 = *(const f32x4*)(kvh + l15*32 + l4*8);
  f32x4 qh0 = *(const f32x4*)(kvh + l15*32 + l4*8 + 4);
  f32x4 ql1 = *(const f32x4*)(kvh + (16 + l15)*32 + l4*8);
  f32x4 qh1 = *(const f32x4*)(kvh + (16 + l15)*32 + l4*8 + 4);
  bf16x8 ka0, ka1;
  #pragma unroll
  for (int j = 0; j < 4; ++j){
    ka0[j] = (__bf16)ql0[j]; ka0[j+4] = (__bf16)qh0[j];
    ka1[j] = (__bf16)ql1[j]; ka1[j+4] = (__bf16)qh1[j];
  }
  __syncthreads();                                  // S0: x staged

  // capture own-stripe x residual (ch oo+16m+l4*4+r, pos 16n+l15) -> regs
  bf16x4 xr[2][4];
  #pragma unroll
  for (int m = 0; m < 2; ++m)
    #pragma unroll
    for (int n = 0; n < 4; ++n)
      xr[m][n] = *(const bf16x4*)(L + swz(16*n + l15, (oo + 16*m + l4*4)*2));

  // ---- Q: head w's 32 q-channels, all 64 pos; q packed to regs ------------
  bf16x4 qk[2][4];
  {
    bf16x8 A0[4], A1[4];
    #pragma unroll
    for (int kf = 0; kf < 4; ++kf){
      A0[kf] = *(const bf16x8*)(w16 + (96*w + l15)*128 + kf*32 + l4*8);
      A1[kf] = *(const bf16x8*)(w16 + (96*w + 16 + l15)*128 + kf*32 + l4*8);
    }
    f32x4 acc[2][4] = {};
    #pragma unroll
    for (int kf = 0; kf < 4; ++kf){
      bf16x8 bn0 = *(const bf16x8*)(L + swz(l15,      kf*64 + l4*16));
      bf16x8 bn1 = *(const bf16x8*)(L + swz(16 + l15, kf*64 + l4*16));
      bf16x8 bn2 = *(const bf16x8*)(L + swz(32 + l15, kf*64 + l4*16));
      bf16x8 bn3 = *(const bf16x8*)(L + swz(48 + l15, kf*64 + l4*16));
      MFMA16(acc[0][0], A0[kf], bn0); MFMA16(acc[0][1], A0[kf], bn1);
      MFMA16(acc[0][2], A0[kf], bn2); MFMA16(acc[0][3], A0[kf], bn3);
      MFMA16(acc[1][0], A1[kf], bn0); MFMA16(acc[1][1], A1[kf], bn1);
      MFMA16(acc[1][2], A1[kf], bn2); MFMA16(acc[1][3], A1[kf], bn3);
    }
    #pragma unroll
    for (int m = 0; m < 2; ++m){
      f32x4 qb = *(const f32x4*)(qkv_b + 96*w + 16*m + l4*4);
      #pragma unroll
      for (int n = 0; n < 4; ++n)
        #pragma unroll
        for (int r = 0; r < 4; ++r) qk[m][n][r] = (__bf16)(acc[m][n][r] + qb[r]);
    }
  }
  __syncthreads();                                  // S1: all x reads done; overlay ok

  // write q to own stripe, then attn (same-wave DS ordering, no barrier)
  #pragma unroll
  for (int m = 0; m < 2; ++m){
    int cB = (oo + 16*m + l4*4) * 2;
    #pragma unroll
    for (int n = 0; n < 4; ++n)
      *(bf16x4*)(L + swz(16*n + l15, cB)) = qk[m][n];
  }
  // ---- attn: ret[d][pos] = kv . q, += xr; own stripe ----------------------
  {
    f32x4 acc[2][4] = {};
    #pragma unroll
    for (int n = 0; n < 4; ++n){
      bf16x8 bq = *(const bf16x8*)(L + swz(16*n + l15, oo*2 + l4*16));
      MFMA16(acc[0][n], ka0, bq);
      MFMA16(acc[1][n], ka1, bq);
    }
    #pragma unroll
    for (int m = 0; m < 2; ++m){
      int cB = (oo + 16*m + l4*4) * 2;
      #pragma unroll
      for (int n = 0; n < 4; ++n){
        bf16x4 pk;
        #pragma unroll
        for (int r = 0; r < 4; ++r) pk[r] = (__bf16)(acc[m][n][r] + (float)xr[m][n][r]);
        *(bf16x4*)(L + swz(16*n + l15, cB)) = pk;
      }
    }
  }
  __syncthreads();                                  // S2: ret complete

  // ---- O1 + gelu ----------------------------------------------------------
  {
    bf16x8 A0[4], A1[4];
    #pragma unroll
    for (int kf = 0; kf < 4; ++kf){
      A0[kf] = *(const bf16x8*)(w1 + (oo + l15)*128 + kf*32 + l4*8);
      A1[kf] = *(const bf16x8*)(w1 + (oo + 16 + l15)*128 + kf*32 + l4*8);
    }
    f32x4 acc1[2][4] = {};
    #pragma unroll
    for (int kf = 0; kf < 4; ++kf){
      bf16x8 bn0 = *(const bf16x8*)(L + swz(l15,      kf*64 + l4*16));
      bf16x8 bn1 = *(const bf16x8*)(L + swz(16 + l15, kf*64 + l4*16));
      bf16x8 bn2 = *(const bf16x8*)(L + swz(32 + l15, kf*64 + l4*16));
      bf16x8 bn3 = *(const bf16x8*)(L + swz(48 + l15, kf*64 + l4*16));
      MFMA16(acc1[0][0], A0[kf], bn0); MFMA16(acc1[0][1], A0[kf], bn1);
      MFMA16(acc1[0][2], A0[kf], bn2); MFMA16(acc1[0][3], A0[kf], bn3);
      MFMA16(acc1[1][0], A1[kf], bn0); MFMA16(acc1[1][1], A1[kf], bn1);
      MFMA16(acc1[1][2], A1[kf], bn2); MFMA16(acc1[1][3], A1[kf], bn3);
    }
    // tanh-GELU in regs BEFORE the barrier (exp VALU overlaps barrier wait)
    bf16x4 hk[2][4];
    #pragma unroll
    for (int m = 0; m < 2; ++m){
      f32x4 bb = *(const f32x4*)(o1b + oo + 16*m + l4*4);
      #pragma unroll
      for (int n = 0; n < 4; ++n)
        #pragma unroll
        for (int r = 0; r < 4; ++r){
          float v = acc1[m][n][r] + bb[r];
          float z = v * (1.5957691216f + 0.0713548164f * v * v);
          hk[m][n][r] = (__bf16)(v / (1.f + __expf(-z)));
        }
    }
    __syncthreads();                                // S3: all ret reads done
    #pragma unroll
    for (int m = 0; m < 2; ++m){
      int cB = (oo + 16*m + l4*4) * 2;
      #pragma unroll
      for (int n = 0; n < 4; ++n)
        *(bf16x4*)(L + swz(16*n + l15, cB)) = hk[m][n];
    }
  }
  __syncthreads();                                  // S4: h complete

  // ---- O2 + bias + residual (xr), store fp32 ------------------------------
  {
    f32x4 acc2[2][4] = {};
    #pragma unroll
    for (int kf = 0; kf < 4; ++kf){
      bf16x8 a0 = *(const bf16x8*)(w2 + (oo + l15)*128 + kf*32 + l4*8);
      bf16x8 a1 = *(const bf16x8*)(w2 + (oo + 16 + l15)*128 + kf*32 + l4*8);
      bf16x8 bn0 = *(const bf16x8*)(L + swz(l15,      kf*64 + l4*16));
      bf16x8 bn1 = *(const bf16x8*)(L + swz(16 + l15, kf*64 + l4*16));
      bf16x8 bn2 = *(const bf16x8*)(L + swz(32 + l15, kf*64 + l4*16));
      bf16x8 bn3 = *(const bf16x8*)(L + swz(48 + l15, kf*64 + l4*16));
      MFMA16(acc2[0][0], a0, bn0); MFMA16(acc2[0][1], a0, bn1);
      MFMA16(acc2[0][2], a0, bn2); MFMA16(acc2[0][3], a0, bn3);
      MFMA16(acc2[1][0], a1, bn0); MFMA16(acc2[1][1], a1, bn1);
      MFMA16(acc2[1][2], a1, bn2); MFMA16(acc2[1][3], a1, bn3);
    }
    #pragma unroll
    for (int m = 0; m < 2; ++m){
      int c0 = oo + 16*m + l4*4;
      f32x4 bb = *(const f32x4*)(o2b + c0);
      #pragma unroll
      for (int n = 0; n < 4; ++n)
        #pragma unroll
        for (int r = 0; r < 4; ++r)
          ob[(size_t)(c0 + r)*65536 + 16*n + l15] = acc2[m][n][r] + bb[r] + (float)xr[m][n][r];
    }
  }
}

// ---- launch ----------------------------------------------------------------
extern "C" void kernel_launch(void* const* d_in, const int* in_sizes, int n_in,
                              void* d_out, int out_size, void* d_ws, size_t ws_size,
                              hipStream_t stream){
  const float* x     = (const float*)d_in[0];
  const float* qkv_w = (const float*)d_in[1];
  const float* qkv_b = (const float*)d_in[2];
  const float* o1w   = (const float*)d_in[3];
  const float* o1b   = (const float*)d_in[4];
  const float* o2w   = (const float*)d_in[5];
  const float* o2b   = (const float*)d_in[6];
  const float* klw   = (const float*)d_in[7];
  const float* klb   = (const float*)d_in[8];
  const float* vlw   = (const float*)d_in[9];
  const float* vlb   = (const float*)d_in[10];

  // part (16 MiB) lives in d_out scratch space: written by k1, read by k15,
  // then k2 overwrites ALL of d_out later in the same stream-ordered launch.
  __bf16* part = (__bf16*)d_out;                       // 2048*4096*2 = 16 MiB < 64 MiB
  float*  kvt  = (float*)d_ws;                         // 32*4096*4 = 512 KiB
  __bf16* w16  = (__bf16*)((char*)d_ws + 524288);      // 81920*2   = 160 KiB

  wprep<<<80, 256, 0, stream>>>(qkv_w, o1w, o2w, w16);
  k1_kv<<<2048, 256, 0, stream>>>(x, w16, qkv_b, klw, klb, vlw, vlb, part);
  k15_reduce<<<256, 256, 0, stream>>>(part, kvt);
  k2_main<<<2048, 256, 0, stream>>>(x, w16, qkv_b, o1b, o2b, kvt, (float*)d_out);
}

// Round 12
// 91.973 us; speedup vs baseline: 1.5218x; 1.0794x over previous
//
#include <hip/hip_runtime.h>
#include <cmath>

// ---- types -----------------------------------------------------------------
typedef float  f32x4  __attribute__((ext_vector_type(4)));
typedef __bf16 bf16x8 __attribute__((ext_vector_type(8)));
typedef __bf16 bf16x4 __attribute__((ext_vector_type(4)));

#define MFMA16(acc, a, b) (acc) = __builtin_amdgcn_mfma_f32_16x16x32_bf16((a), (b), (acc), 0, 0, 0)

// Geometry: x [B=2, C=128, D=16, H=64, W=64] fp32; flat = b*8388608 + c*65536 + d*4096 + hw.
// qkv_w rows: head h occupies [96h, 96h+96): q +0, k +32, v +64.
// Attention-output channel numbering: ch = 32h + d (head-major) == raw channel.
//
// ALGEBRAIC FUSION (r12): ret = kv.(Wq x + bq) + x  ==  (kv.Wq + I).x + kv.bq
// so per-bd W_eff[128x128] and b_eff[128] replace the q GEMM + attn phase.

// LDS swizzles (XOR keeps 16B-aligned access conflict-light, T2/G4)
__device__ __forceinline__ int swz(int row, int colByte){ return row*256 + (colByte ^ ((row & 7) << 4)); }   // pitch 256B
__device__ __forceinline__ int swzP(int row, int colByte){ return row*128 + (colByte ^ ((row & 7) << 4)); }  // pitch 128B

// coalesced fp32 x-tile load: 64 pos x 128 ch; thread t: pos=t&63 (256B/instr), 32 floats
__device__ __forceinline__ void loadx(float* sx, const float* __restrict__ xb, int t){
  int p = t & 63, cg = t >> 6;
  const float* col = xb + p;
  #pragma unroll
  for (int i = 0; i < 4; ++i)
    #pragma unroll
    for (int j = 0; j < 8; ++j)
      sx[i*8 + j] = col[(cg*8 + i*32 + j) * 65536];
}
// cvt + LDS write of staged regs -> bf16 [pos][ch] swizzled tile
__device__ __forceinline__ void writex(const float* sx, char* ldsX, int t){
  int p = t & 63, cg = t >> 6;
  #pragma unroll
  for (int i = 0; i < 4; ++i){
    bf16x8 u;
    #pragma unroll
    for (int j = 0; j < 8; ++j) u[j] = (__bf16)sx[i*8 + j];
    *(bf16x8*)(ldsX + swz(p, cg*16 + i*64)) = u;
  }
}

// ---- W-prep: fp32 weights -> bf16 once (qkv_w | o1w | o2w concatenated) ----
__global__ __launch_bounds__(256) void wprep(const float* __restrict__ qkv_w,
                                             const float* __restrict__ o1w,
                                             const float* __restrict__ o2w,
                                             __bf16* __restrict__ w16){
  int e = (blockIdx.x * 256 + threadIdx.x) * 4;   // 80 blocks -> 81920 elems
  const float* src; int off;
  if (e < 49152)      { src = qkv_w; off = e; }
  else if (e < 65536) { src = o1w;   off = e - 49152; }
  else                { src = o2w;   off = e - 65536; }
  f32x4 v = *(const f32x4*)(src + off);
  bf16x4 o;
  #pragma unroll
  for (int r = 0; r < 4; ++r) o[r] = (__bf16)v[r];
  *(bf16x4*)(w16 + e) = o;
}

// ---- K1: k/v projection + LayerNorm + per-block kv partial (r9 exact) ------
// grid 2048 = 32 bd x 64 tiles of 64 pos, single chunk, 2 barriers (~33us).
// LDS 32K: x tile 16K (per-wave v' overlaid after S_b), 4x4K k' scratch.
// Partials go to d_out (16MB scratch, k2 overwrites it later in the launch).
__global__ __launch_bounds__(256) void k1_kv(
    const float* __restrict__ x, const __bf16* __restrict__ w16, const float* __restrict__ qkv_b,
    const float* __restrict__ klw, const float* __restrict__ klb,
    const float* __restrict__ vlw, const float* __restrict__ vlb,
    __bf16* __restrict__ part){
  __shared__ char ldsX[16384];     // x [64 pos][256B] -> per-wave v' [32][64] @ w*4096
  __shared__ char ksS[4][4096];    // per-wave k' [32 ch][64 pos] bf16, pitch 128B
  int t = threadIdx.x, lane = t & 63, w = t >> 6, l15 = lane & 15, l4 = lane >> 4;
  int bx = blockIdx.x, bd = bx >> 6, b = bd >> 4, d = bd & 15;
  const float* xb = x + (size_t)b*8388608 + d*4096 + (bx & 63)*64;
  char* ks = ksS[w];
  char* vs = ldsX + w * 4096;

  {
    float sx[32];
    loadx(sx, xb, t);
    writex(sx, ldsX, t);
  }
  __syncthreads();                                  // S_a: x staged

  bf16x4 pv0[4], pv1[4];           // v' packed bf16, lives across S_b (8 VGPRs)
  // ---- phase 0: k -> LN -> ks (write now); phase 1: v -> LN -> pack -------
  #pragma unroll
  for (int ph = 0; ph < 2; ++ph){
    int po = 96*w + 32 + 32*ph;
    f32x4 acc[2][4] = {};
    #pragma unroll
    for (int kf = 0; kf < 4; ++kf){
      bf16x8 a0 = *(const bf16x8*)(w16 + (po + l15)*128 + kf*32 + l4*8);
      bf16x8 a1 = *(const bf16x8*)(w16 + (po + 16 + l15)*128 + kf*32 + l4*8);
      bf16x8 bn0 = *(const bf16x8*)(ldsX + swz(l15,      kf*64 + l4*16));
      bf16x8 bn1 = *(const bf16x8*)(ldsX + swz(16 + l15, kf*64 + l4*16));
      bf16x8 bn2 = *(const bf16x8*)(ldsX + swz(32 + l15, kf*64 + l4*16));
      bf16x8 bn3 = *(const bf16x8*)(ldsX + swz(48 + l15, kf*64 + l4*16));
      MFMA16(acc[0][0], a0, bn0); MFMA16(acc[0][1], a0, bn1);
      MFMA16(acc[0][2], a0, bn2); MFMA16(acc[0][3], a0, bn3);
      MFMA16(acc[1][0], a1, bn0); MFMA16(acc[1][1], a1, bn1);
      MFMA16(acc[1][2], a1, bn2); MFMA16(acc[1][3], a1, bn3);
    }
    const float* lwp = (ph ? vlw : klw) + 32*w;
    const float* lbp = (ph ? vlb : klb) + 32*w;
    f32x4 b0  = *(const f32x4*)(qkv_b + po + l4*4);
    f32x4 b1  = *(const f32x4*)(qkv_b + po + 16 + l4*4);
    f32x4 lw0 = *(const f32x4*)(lwp + l4*4), lw1 = *(const f32x4*)(lwp + 16 + l4*4);
    f32x4 lb0 = *(const f32x4*)(lbp + l4*4), lb1 = *(const f32x4*)(lbp + 16 + l4*4);
    #pragma unroll
    for (int n = 0; n < 4; ++n){
      f32x4 v0 = acc[0][n] + b0;
      f32x4 v1 = acc[1][n] + b1;
      // LN over 32 ch per pos (ddof=1, denom = std+eps): in-lane 8 + xor 16,32
      float s1 = v0[0]+v0[1]+v0[2]+v0[3] + v1[0]+v1[1]+v1[2]+v1[3];
      float s2 = v0[0]*v0[0]+v0[1]*v0[1]+v0[2]*v0[2]+v0[3]*v0[3]
               + v1[0]*v1[0]+v1[1]*v1[1]+v1[2]*v1[2]+v1[3]*v1[3];
      s1 += __shfl_xor(s1, 16); s2 += __shfl_xor(s2, 16);
      s1 += __shfl_xor(s1, 32); s2 += __shfl_xor(s2, 32);
      float m   = s1 * (1.f/32.f);
      float var = fmaxf((s2 - 32.f*m*m) * (1.f/31.f), 0.f);
      float inv = 1.f / (sqrtf(var) + 1e-5f);
      v0 = (v0 - m) * inv * lw0 + lb0;
      v1 = (v1 - m) * inv * lw1 + lb1;
      if (ph == 0){
        int pB = (16*n + l15) * 2;
        #pragma unroll
        for (int r = 0; r < 4; ++r){
          *(__bf16*)(ks + swzP(l4*4 + r, pB))      = (__bf16)v0[r];
          *(__bf16*)(ks + swzP(16 + l4*4 + r, pB)) = (__bf16)v1[r];
        }
      } else {
        #pragma unroll
        for (int r = 0; r < 4; ++r){ pv0[n][r] = (__bf16)v0[r]; pv1[n][r] = (__bf16)v1[r]; }
      }
    }
  }
  __syncthreads();                                  // S_b: all x reads done; overlay v'
  #pragma unroll
  for (int n = 0; n < 4; ++n){
    int pB = (16*n + l15) * 2;
    #pragma unroll
    for (int r = 0; r < 4; ++r){
      *(__bf16*)(vs + swzP(l4*4 + r, pB))      = pv0[n][r];
      *(__bf16*)(vs + swzP(16 + l4*4 + r, pB)) = pv1[n][r];
    }
  }
  // outer product kv[d][c] = sum_pos v'[d,pos] k'[c,pos] (K=64);
  // same-wave ds_write->ds_read (in-order DS pipe), no barrier needed.
  f32x4 kv[2][2] = {};
  #pragma unroll
  for (int kf = 0; kf < 2; ++kf){
    bf16x8 av0 = *(const bf16x8*)(vs + swzP(l15,      kf*64 + l4*16));
    bf16x8 av1 = *(const bf16x8*)(vs + swzP(16 + l15, kf*64 + l4*16));
    bf16x8 bk0 = *(const bf16x8*)(ks + swzP(l15,      kf*64 + l4*16));
    bf16x8 bk1 = *(const bf16x8*)(ks + swzP(16 + l15, kf*64 + l4*16));
    MFMA16(kv[0][0], av0, bk0); MFMA16(kv[0][1], av0, bk1);
    MFMA16(kv[1][0], av1, bk0); MFMA16(kv[1][1], av1, bk1);
  }

  // store partial: part[bx][h=w][d][c], c fast
  __bf16* pb = part + (size_t)bx*4096 + w*1024;
  #pragma unroll
  for (int m = 0; m < 2; ++m)
    #pragma unroll
    for (int n = 0; n < 2; ++n)
      #pragma unroll
      for (int r = 0; r < 4; ++r)
        pb[(16*m + l4*4 + r)*32 + 16*n + l15] = (__bf16)kv[m][n][r];
}

// ---- KWEFF: reduce partials + build W_eff = kv.Wq + I, b_eff = kv.bq -------
// grid 128 = 32 bd x 4 heads; block 256. Replaces k15 AND k2's q+attn phases.
__global__ __launch_bounds__(256) void kweff(
    const __bf16* __restrict__ part, const __bf16* __restrict__ w16,
    const float* __restrict__ qkv_b,
    __bf16* __restrict__ weff, float* __restrict__ beff){
  __shared__ float kvsh[1024];     // kv[d][c] f32 for this (bd, h)
  int t = threadIdx.x, bx = blockIdx.x;
  int bd = bx >> 2, h = bx & 3;

  // reduce 64 partials (scale 1/4096)
  {
    f32x4 s = {0.f, 0.f, 0.f, 0.f};
    const __bf16* pb = part + (size_t)bd*64*4096 + h*1024 + t*4;
    for (int sub = 0; sub < 64; ++sub){
      bf16x4 p = *(const bf16x4*)(pb + (size_t)sub*4096);
      #pragma unroll
      for (int r = 0; r < 4; ++r) s[r] += (float)p[r];
    }
    #pragma unroll
    for (int r = 0; r < 4; ++r) kvsh[t*4 + r] = s[r] * (1.f/4096.f);
  }
  __syncthreads();

  // W_eff[32h+dd][j] = sum_c kv[dd][c] * Wq[96h+c][j]  (+1 on diagonal)
  int j = t & 127, half = t >> 7;
  float wq[32];
  #pragma unroll
  for (int c = 0; c < 32; ++c) wq[c] = (float)w16[(96*h + c)*128 + j];
  #pragma unroll
  for (int dq = 0; dq < 16; ++dq){
    int dd = half*16 + dq;
    float s = 0.f;
    #pragma unroll
    for (int c = 0; c < 32; ++c) s += kvsh[dd*32 + c] * wq[c];
    if (32*h + dd == j) s += 1.f;                  // fold +x residual
    weff[(size_t)bd*16384 + (32*h + dd)*128 + j] = (__bf16)s;
  }
  // b_eff[32h+dd] = sum_c bq[96h+c] * kv[dd][c]
  if (t < 32){
    float s = 0.f;
    #pragma unroll
    for (int c = 0; c < 32; ++c) s += qkv_b[96*h + c] * kvsh[t*32 + c];
    beff[bd*128 + 32*h + t] = s;
  }
}

// ---- K2: G1(W_eff) -> G2(o1+gelu) -> G3(o2 + bias + x) ---------------------
// grid 2048, one 64-pos tile; block 256 = 4 waves, wave w owns 32 out-ch per
// GEMM. Two 16KB buffers (lx persists for the final residual). 4 barriers.
// One GEMM phase FEWER than r9 (q+attn collapsed into G1 via W_eff).
__global__ __launch_bounds__(256) void k2_main(
    const float* __restrict__ x, const __bf16* __restrict__ w16,
    const __bf16* __restrict__ weff, const float* __restrict__ beff,
    const float* __restrict__ o1b, const float* __restrict__ o2b,
    float* __restrict__ out){
  __shared__ char lx[16384];   // x tile [64 pos][128 ch] bf16 (persists)
  __shared__ char wk[16384];   // ret -> h work buffer
  int t = threadIdx.x, lane = t & 63, w = t >> 6, l15 = lane & 15, l4 = lane >> 4;
  int bx = blockIdx.x, bd = bx >> 6, b = bd >> 4, d = bd & 15;
  size_t gofs = (size_t)b*8388608 + d*4096 + (bx & 63)*64;
  const float* xb = x + gofs;
  float* ob = out + gofs;
  const __bf16* w1 = w16 + 49152;
  const __bf16* w2 = w16 + 65536;
  const __bf16* we = weff + (size_t)bd*16384;
  int oo = 32 * w;

  {
    float sx[32];
    loadx(sx, xb, t);
    writex(sx, lx, t);
  }
  __syncthreads();                                  // S0: x staged

  // ---- G1: ret = W_eff . x + b_eff -> wk own stripe (no barrier needed) ---
  {
    bf16x8 A0[4], A1[4];
    #pragma unroll
    for (int kf = 0; kf < 4; ++kf){
      A0[kf] = *(const bf16x8*)(we + (oo + l15)*128 + kf*32 + l4*8);
      A1[kf] = *(const bf16x8*)(we + (oo + 16 + l15)*128 + kf*32 + l4*8);
    }
    f32x4 acc[2][4] = {};
    #pragma unroll
    for (int kf = 0; kf < 4; ++kf){
      bf16x8 bn0 = *(const bf16x8*)(lx + swz(l15,      kf*64 + l4*16));
      bf16x8 bn1 = *(const bf16x8*)(lx + swz(16 + l15, kf*64 + l4*16));
      bf16x8 bn2 = *(const bf16x8*)(lx + swz(32 + l15, kf*64 + l4*16));
      bf16x8 bn3 = *(const bf16x8*)(lx + swz(48 + l15, kf*64 + l4*16));
      MFMA16(acc[0][0], A0[kf], bn0); MFMA16(acc[0][1], A0[kf], bn1);
      MFMA16(acc[0][2], A0[kf], bn2); MFMA16(acc[0][3], A0[kf], bn3);
      MFMA16(acc[1][0], A1[kf], bn0); MFMA16(acc[1][1], A1[kf], bn1);
      MFMA16(acc[1][2], A1[kf], bn2); MFMA16(acc[1][3], A1[kf], bn3);
    }
    #pragma unroll
    for (int m = 0; m < 2; ++m){
      f32x4 bb = *(const f32x4*)(beff + bd*128 + oo + 16*m + l4*4);
      int cB = (oo + 16*m + l4*4) * 2;
      #pragma unroll
      for (int n = 0; n < 4; ++n){
        bf16x4 pk;
        #pragma unroll
        for (int r = 0; r < 4; ++r) pk[r] = (__bf16)(acc[m][n][r] + bb[r]);
        *(bf16x4*)(wk + swz(16*n + l15, cB)) = pk;
      }
    }
  }
  __syncthreads();                                  // S1: ret complete

  // ---- G2: O1 + gelu ------------------------------------------------------
  {
    bf16x8 A0[4], A1[4];
    #pragma unroll
    for (int kf = 0; kf < 4; ++kf){
      A0[kf] = *(const bf16x8*)(w1 + (oo + l15)*128 + kf*32 + l4*8);
      A1[kf] = *(const bf16x8*)(w1 + (oo + 16 + l15)*128 + kf*32 + l4*8);
    }
    f32x4 acc1[2][4] = {};
    #pragma unroll
    for (int kf = 0; kf < 4; ++kf){
      bf16x8 bn0 = *(const bf16x8*)(wk + swz(l15,      kf*64 + l4*16));
      bf16x8 bn1 = *(const bf16x8*)(wk + swz(16 + l15, kf*64 + l4*16));
      bf16x8 bn2 = *(const bf16x8*)(wk + swz(32 + l15, kf*64 + l4*16));
      bf16x8 bn3 = *(const bf16x8*)(wk + swz(48 + l15, kf*64 + l4*16));
      MFMA16(acc1[0][0], A0[kf], bn0); MFMA16(acc1[0][1], A0[kf], bn1);
      MFMA16(acc1[0][2], A0[kf], bn2); MFMA16(acc1[0][3], A0[kf], bn3);
      MFMA16(acc1[1][0], A1[kf], bn0); MFMA16(acc1[1][1], A1[kf], bn1);
      MFMA16(acc1[1][2], A1[kf], bn2); MFMA16(acc1[1][3], A1[kf], bn3);
    }
    // tanh-GELU in regs BEFORE the barrier (exp VALU overlaps barrier wait)
    bf16x4 hk[2][4];
    #pragma unroll
    for (int m = 0; m < 2; ++m){
      f32x4 bb = *(const f32x4*)(o1b + oo + 16*m + l4*4);
      #pragma unroll
      for (int n = 0; n < 4; ++n)
        #pragma unroll
        for (int r = 0; r < 4; ++r){
          float v = acc1[m][n][r] + bb[r];
          float z = v * (1.5957691216f + 0.0713548164f * v * v);
          hk[m][n][r] = (__bf16)(v / (1.f + __expf(-z)));
        }
    }
    __syncthreads();                                // S2: all ret reads done
    #pragma unroll
    for (int m = 0; m < 2; ++m){
      int cB = (oo + 16*m + l4*4) * 2;
      #pragma unroll
      for (int n = 0; n < 4; ++n)
        *(bf16x4*)(wk + swz(16*n + l15, cB)) = hk[m][n];
    }
  }
  __syncthreads();                                  // S3: h complete

  // ---- G3: O2 + bias + residual (from intact lx), store fp32 --------------
  {
    bf16x8 A0[4], A1[4];
    #pragma unroll
    for (int kf = 0; kf < 4; ++kf){
      A0[kf] = *(const bf16x8*)(w2 + (oo + l15)*128 + kf*32 + l4*8);
      A1[kf] = *(const bf16x8*)(w2 + (oo + 16 + l15)*128 + kf*32 + l4*8);
    }
    f32x4 acc2[2][4] = {};
    #pragma unroll
    for (int kf = 0; kf < 4; ++kf){
      bf16x8 bn0 = *(const bf16x8*)(wk + swz(l15,      kf*64 + l4*16));
      bf16x8 bn1 = *(const bf16x8*)(wk + swz(16 + l15, kf*64 + l4*16));
      bf16x8 bn2 = *(const bf16x8*)(wk + swz(32 + l15, kf*64 + l4*16));
      bf16x8 bn3 = *(const bf16x8*)(wk + swz(48 + l15, kf*64 + l4*16));
      MFMA16(acc2[0][0], A0[kf], bn0); MFMA16(acc2[0][1], A0[kf], bn1);
      MFMA16(acc2[0][2], A0[kf], bn2); MFMA16(acc2[0][3], A0[kf], bn3);
      MFMA16(acc2[1][0], A1[kf], bn0); MFMA16(acc2[1][1], A1[kf], bn1);
      MFMA16(acc2[1][2], A1[kf], bn2); MFMA16(acc2[1][3], A1[kf], bn3);
    }
    #pragma unroll
    for (int m = 0; m < 2; ++m){
      int c0 = oo + 16*m + l4*4;
      f32x4 bb = *(const f32x4*)(o2b + c0);
      #pragma unroll
      for (int n = 0; n < 4; ++n){
        bf16x4 xv = *(const bf16x4*)(lx + swz(16*n + l15, c0*2));
        #pragma unroll
        for (int r = 0; r < 4; ++r)
          ob[(size_t)(c0 + r)*65536 + 16*n + l15] = acc2[m][n][r] + bb[r] + (float)xv[r];
      }
    }
  }
}

// ---- launch ----------------------------------------------------------------
extern "C" void kernel_launch(void* const* d_in, const int* in_sizes, int n_in,
                              void* d_out, int out_size, void* d_ws, size_t ws_size,
                              hipStream_t stream){
  const float* x     = (const float*)d_in[0];
  const float* qkv_w = (const float*)d_in[1];
  const float* qkv_b = (const float*)d_in[2];
  const float* o1w   = (const float*)d_in[3];
  const float* o1b   = (const float*)d_in[4];
  const float* o2w   = (const float*)d_in[5];
  const float* o2b   = (const float*)d_in[6];
  const float* klw   = (const float*)d_in[7];
  const float* klb   = (const float*)d_in[8];
  const float* vlw   = (const float*)d_in[9];
  const float* vlb   = (const float*)d_in[10];

  // part (16 MiB) lives in d_out scratch space: written by k1, read by kweff,
  // then k2 overwrites ALL of d_out later in the same stream-ordered launch.
  __bf16* part = (__bf16*)d_out;                       // 2048*4096*2 = 16 MiB
  __bf16* weff = (__bf16*)d_ws;                        // 32*128*128*2 = 1 MiB
  float*  beff = (float*)((char*)d_ws + 1048576);      // 32*128*4 = 16 KiB
  __bf16* w16  = (__bf16*)((char*)d_ws + 1064960);     // 81920*2  = 160 KiB

  wprep<<<80, 256, 0, stream>>>(qkv_w, o1w, o2w, w16);
  k1_kv<<<2048, 256, 0, stream>>>(x, w16, qkv_b, klw, klb, vlw, vlb, part);
  kweff<<<128, 256, 0, stream>>>(part, w16, qkv_b, weff, beff);
  k2_main<<<2048, 256, 0, stream>>>(x, w16, weff, beff, o1b, o2b, (float*)d_out);
}